// Round 19
// baseline (60.198 us; speedup 1.0000x reference)
//
#include <hip/hip_runtime.h>

// KiloNeRF fused MLP — 32x32x16 MFMA, layer-folded, split-C version.
// R19 = R18 with intra-layer MFMA parallelism (split-C): each 32-wide
// layer's two k-half MFMAs become independent (bias/partial in one C-init,
// zero in the other) + a VALU merge, removing 3 serial MFMA latencies from
// the per-tile chain (chain length is what has tracked dur all session).
//  - cv (views+bvEff) issues right after L0 (depends only on bx) and
//    overlaps L1's latency; it is the C-init of the fold's lo half.
//  - rgb split-C merge only needs rows 0..2 (3 adds at store).
//  - __launch_bounds__(256,3) matches achieved occupancy, giving the
//    allocator slack to avoid AGPR<->VGPR shuttle copies.
//  - Wc = WF·WVf composed in-wave via 2 MFMA32s (R18); bvEff per-lane.
// chain: bx -> L0 (|| cv) -> pack -> L1(p0||p1)+add -> pack (+sigma fdot2)
//        -> fold(q0||q1)+add -> pack -> rgb(r0||r1) -> store(+3 adds)

#define NPTS   4194304
#define NT32   (NPTS / 32)

typedef _Float16 f16;
typedef _Float16 f16x2 __attribute__((ext_vector_type(2)));
typedef _Float16 f16x8 __attribute__((ext_vector_type(8)));
typedef __fp16   h16x2 __attribute__((ext_vector_type(2)));
typedef float    f32x16 __attribute__((ext_vector_type(16)));

union H8 { f16x8 v; unsigned u[4]; };

static __device__ __forceinline__ unsigned pkrtz(float a, float b) {
    return __builtin_bit_cast(unsigned, __builtin_amdgcn_cvt_pkrtz(a, b));
}
static __device__ __forceinline__ unsigned relu2(unsigned w) {
    f16x2 h = __builtin_bit_cast(f16x2, w);
    f16x2 z = (f16x2)(f16)0.f;
    return __builtin_bit_cast(unsigned, __builtin_elementwise_max(h, z));
}
static __device__ __forceinline__ float fdot2(unsigned a, unsigned b, float c) {
    return __builtin_amdgcn_fdot2(__builtin_bit_cast(h16x2, a),
                                  __builtin_bit_cast(h16x2, b), c, false);
}

#define MFMA32(A, B, C) __builtin_amdgcn_mfma_f32_32x32x16_f16((A), (B), (C), 0, 0, 0)

__global__ __launch_bounds__(256, 3) void kilonerf_r19(
    const float* __restrict__ x,
    const float* __restrict__ w0, const float* __restrict__ b0,
    const float* __restrict__ w1, const float* __restrict__ b1,
    const float* __restrict__ wf, const float* __restrict__ bf,
    const float* __restrict__ ws, const float* __restrict__ bs,
    const float* __restrict__ wv, const float* __restrict__ bv,
    const float* __restrict__ wr, const float* __restrict__ br,
    float* __restrict__ out)
{
    const int lane = threadIdx.x & 63;
    const int m  = lane & 31;     // output channel (A row) / point (B,C col)
    const int hi = lane >> 5;     // lane half

    int sj[8], row[16];
#pragma unroll
    for (int j = 0; j < 8; ++j)  sj[j]  = (j & 3) + 8 * (j >> 2) + 4 * hi;
#pragma unroll
    for (int r = 0; r < 16; ++r) row[r] = (r & 3) + 8 * (r >> 2) + 4 * hi;

    f32x16 zf;
#pragma unroll
    for (int r = 0; r < 16; ++r) zf[r] = 0.f;

    // ---- one-time: bvEff[m] = bv[m] + sum_t bf[t]*wv[t*32+m] ----
    float bve = bv[m];
#pragma unroll 8
    for (int t = 0; t < 32; ++t) bve = fmaf(wv[t * 32 + m], bf[t], bve);

    // ---- one-time: Wc = WF·WVf via 2 MFMA32s ----
    f16x8 afw1, afw2, bwv1, bwv2;
#pragma unroll
    for (int j = 0; j < 8; ++j) {
        const int k = sj[j];
        afw1[j] = (f16)wf[m * 32 + k];
        afw2[j] = (f16)wf[m * 32 + 16 + k];
        bwv1[j] = (f16)wv[k * 32 + m];
        bwv2[j] = (f16)wv[(16 + k) * 32 + m];
    }
    f32x16 dwc = MFMA32(afw1, bwv1, zf);
    dwc = MFMA32(afw2, bwv2, dwc);
    f16x8 awclo, awchi;
#pragma unroll
    for (int j = 0; j < 8; ++j) {
        awclo[j] = (f16)dwc[j];
        awchi[j] = (f16)dwc[8 + j];
    }

    // ---- one-time weight fragment gathers (all cached loads) ----
    f16x8 aw0x, awv2x, aw1lo, aw1hi, awrlo, awrhi;
#pragma unroll
    for (int j = 0; j < 8; ++j) {
        const int k = sj[j];
        aw0x[j]  = (k < 3) ? (f16)w0[k * 32 + m]
                  : (k == 3 ? (f16)b0[m] : (f16)0.f);
        awv2x[j] = (k >= 4 && k < 7) ? (f16)wv[(32 + (k - 4)) * 32 + m]
                  : (k == 7 ? (f16)bve : (f16)0.f);
        aw1lo[j] = (f16)w1[k * 32 + m];
        aw1hi[j] = (f16)w1[(16 + k) * 32 + m];
        awrlo[j] = (m < 3) ? (f16)wr[k * 3 + m] : (f16)0.f;
        awrhi[j] = (m < 3) ? (f16)wr[(16 + k) * 3 + m] : (f16)0.f;
    }

    // sigma weights packed f16: word w pairs channels (row[2w], row[2w+1])
    unsigned wspk[8];
#pragma unroll
    for (int w = 0; w < 8; ++w)
        wspk[w] = pkrtz(ws[row[2 * w]], ws[row[2 * w + 1]]);

    // L1 bias C-init
    f32x16 b1c;
#pragma unroll
    for (int r = 0; r < 16; ++r) b1c[r] = b1[row[r]];

    const float br0 = br[0], br1 = br[1], br2 = br[2], bs0 = bs[0];

    const int wslot  = blockIdx.x * 4 + (threadIdx.x >> 6);
    const int nslots = gridDim.x * 4;   // 8192 waves

    // ---- prefetch first tile's x ----
    float2 cx0, cx1, cx2;
    {
        const float2* xp2 = reinterpret_cast<const float2*>(
            x + (size_t)(wslot * 32 + m) * 6);
        cx0 = xp2[0]; cx1 = xp2[1]; cx2 = xp2[2];
    }

    for (int tile = wslot; tile < NT32; tile += nslots) {
        // issue next tile's loads early (wraps to a valid address at end)
        int np = tile + nslots; if (np >= NT32) np = wslot;
        const float2* xn = reinterpret_cast<const float2*>(
            x + (size_t)(np * 32 + m) * 6);
        float2 nx0 = xn[0], nx1 = xn[1], nx2 = xn[2];

        // merged input fragment: hi=0 -> {p0,p1,p2,1} at k=0..3,
        //                        hi=1 -> {v0,v1,v2,1} at k=4..7
        const float fa = hi ? cx1.y : cx0.x;
        const float fb = hi ? cx2.x : cx0.y;
        const float fc = hi ? cx2.y : cx1.x;
        H8 bx;
        bx.u[0] = pkrtz(fa, fb);
        bx.u[1] = pkrtz(fc, 1.0f);
        bx.u[2] = 0u;
        bx.u[3] = 0u;

        // ---- layer 0 (+b0) and view-partial cv (+bvEff): both from bx,
        //      issued back-to-back; cv's latency hides under L0+L1 ----
        f32x16 c0 = MFMA32(aw0x, bx.v, zf);
        f32x16 cv = MFMA32(awv2x, bx.v, zf);

        H8 blo, bhi;
        blo.u[0] = relu2(pkrtz(c0[0], c0[1]));
        blo.u[1] = relu2(pkrtz(c0[2], c0[3]));
        blo.u[2] = relu2(pkrtz(c0[4], c0[5]));
        blo.u[3] = relu2(pkrtz(c0[6], c0[7]));
        bhi.u[0] = relu2(pkrtz(c0[8], c0[9]));
        bhi.u[1] = relu2(pkrtz(c0[10], c0[11]));
        bhi.u[2] = relu2(pkrtz(c0[12], c0[13]));
        bhi.u[3] = relu2(pkrtz(c0[14], c0[15]));

        // ---- layer 1 split-C: two independent MFMAs + VALU merge ----
        f32x16 p0 = MFMA32(aw1lo, blo.v, b1c);
        f32x16 p1 = MFMA32(aw1hi, bhi.v, zf);
        f32x16 c1 = p0 + p1;

        blo.u[0] = relu2(pkrtz(c1[0], c1[1]));
        blo.u[1] = relu2(pkrtz(c1[2], c1[3]));
        blo.u[2] = relu2(pkrtz(c1[4], c1[5]));
        blo.u[3] = relu2(pkrtz(c1[6], c1[7]));
        bhi.u[0] = relu2(pkrtz(c1[8], c1[9]));
        bhi.u[1] = relu2(pkrtz(c1[10], c1[11]));
        bhi.u[2] = relu2(pkrtz(c1[12], c1[13]));
        bhi.u[3] = relu2(pkrtz(c1[14], c1[15]));

        // sigma = ws . relu(h1) via packed dot2 (f32 accumulate)
        float s0 = 0.f, s1 = 0.f;
#pragma unroll
        for (int w = 0; w < 4; ++w) {
            s0 = fdot2(blo.u[w], wspk[w], s0);
            s1 = fdot2(bhi.u[w], wspk[4 + w], s1);
        }
        float sg = s0 + s1;
        sg += __shfl_xor(sg, 32);

        // ---- fold split-C: q0 carries cv (ready long ago), q1 zero ----
        f32x16 q0 = MFMA32(awclo, blo.v, cv);
        f32x16 q1 = MFMA32(awchi, bhi.v, zf);
        f32x16 cc = q0 + q1;

        blo.u[0] = relu2(pkrtz(cc[0], cc[1]));
        blo.u[1] = relu2(pkrtz(cc[2], cc[3]));
        blo.u[2] = relu2(pkrtz(cc[4], cc[5]));
        blo.u[3] = relu2(pkrtz(cc[6], cc[7]));
        bhi.u[0] = relu2(pkrtz(cc[8], cc[9]));
        bhi.u[1] = relu2(pkrtz(cc[10], cc[11]));
        bhi.u[2] = relu2(pkrtz(cc[12], cc[13]));
        bhi.u[3] = relu2(pkrtz(cc[14], cc[15]));

        // ---- rgb split-C: rows 0..2 merged at store (3 adds) ----
        f32x16 r0 = MFMA32(awrlo, blo.v, zf);
        f32x16 r1 = MFMA32(awrhi, bhi.v, zf);

        // ---- store: hi==0 lanes hold rgb rows 0..2 for their point ----
        if (hi == 0) {
            float4 o = make_float4(r0[0] + r1[0] + br0,
                                   r0[1] + r1[1] + br1,
                                   r0[2] + r1[2] + br2, sg + bs0);
            *reinterpret_cast<float4*>(out + (size_t)(tile * 32 + m) * 4) = o;
        }

        cx0 = nx0; cx1 = nx1; cx2 = nx2;
    }
}

extern "C" void kernel_launch(void* const* d_in, const int* in_sizes, int n_in,
                              void* d_out, int out_size, void* d_ws, size_t ws_size,
                              hipStream_t stream) {
    const float* x  = (const float*)d_in[0];
    const float* w0 = (const float*)d_in[1];
    const float* b0 = (const float*)d_in[2];
    const float* w1 = (const float*)d_in[3];
    const float* b1 = (const float*)d_in[4];
    const float* wf = (const float*)d_in[5];
    const float* bf = (const float*)d_in[6];
    const float* ws = (const float*)d_in[7];
    const float* bs = (const float*)d_in[8];
    const float* wv = (const float*)d_in[9];
    const float* bv = (const float*)d_in[10];
    const float* wr = (const float*)d_in[11];
    const float* br = (const float*)d_in[12];
    float* out = (float*)d_out;

    dim3 block(256);
    dim3 grid(2048);
    kilonerf_r19<<<grid, block, 0, stream>>>(x, w0, b0, w1, b1, wf, bf,
                                             ws, bs, wv, bv, wr, br, out);
}

// Round 20
// 57.562 us; speedup vs baseline: 1.0458x; 1.0458x over previous
//
#include <hip/hip_runtime.h>

// KiloNeRF fused MLP — 32x32x16 MFMA, layer-folded, cross-iteration
// software-pipelined version.
// R20 = R18 (best, 55.25us) + pipeline the chain HEAD across iterations:
// tile t+1's L0 (c0) and view-partial (cv) MFMAs issue during tile t's
// body, so at iteration start c0/cv are a full iteration old — L0 MFMA
// latency and the x-load latency drop off the per-tile critical path.
// Chain: pack(h0) -> L1(x2 chained) -> pack(+sigma fdot2) -> fold(x2, C=cv)
//        -> pack -> rgb(x2) -> store.  (3 serial MFMA stages, was 4+load)
//  - Wc = WF·WVf composed in-wave via 2 MFMA32s; bvEff per-lane (R18).
//  - #pragma unroll 2 so the c0c=c0n rotation is renamed, not copied.
//  - x prefetch now runs a full iteration ahead (~1000cyc > HBM miss).

#define NPTS   4194304
#define NT32   (NPTS / 32)

typedef _Float16 f16;
typedef _Float16 f16x2 __attribute__((ext_vector_type(2)));
typedef _Float16 f16x8 __attribute__((ext_vector_type(8)));
typedef __fp16   h16x2 __attribute__((ext_vector_type(2)));
typedef float    f32x16 __attribute__((ext_vector_type(16)));

union H8 { f16x8 v; unsigned u[4]; };

static __device__ __forceinline__ unsigned pkrtz(float a, float b) {
    return __builtin_bit_cast(unsigned, __builtin_amdgcn_cvt_pkrtz(a, b));
}
static __device__ __forceinline__ unsigned relu2(unsigned w) {
    f16x2 h = __builtin_bit_cast(f16x2, w);
    f16x2 z = (f16x2)(f16)0.f;
    return __builtin_bit_cast(unsigned, __builtin_elementwise_max(h, z));
}
static __device__ __forceinline__ float fdot2(unsigned a, unsigned b, float c) {
    return __builtin_amdgcn_fdot2(__builtin_bit_cast(h16x2, a),
                                  __builtin_bit_cast(h16x2, b), c, false);
}

#define MFMA32(A, B, C) __builtin_amdgcn_mfma_f32_32x32x16_f16((A), (B), (C), 0, 0, 0)

__global__ __launch_bounds__(256, 4) void kilonerf_r20(
    const float* __restrict__ x,
    const float* __restrict__ w0, const float* __restrict__ b0,
    const float* __restrict__ w1, const float* __restrict__ b1,
    const float* __restrict__ wf, const float* __restrict__ bf,
    const float* __restrict__ ws, const float* __restrict__ bs,
    const float* __restrict__ wv, const float* __restrict__ bv,
    const float* __restrict__ wr, const float* __restrict__ br,
    float* __restrict__ out)
{
    const int lane = threadIdx.x & 63;
    const int m  = lane & 31;     // output channel (A row) / point (B,C col)
    const int hi = lane >> 5;     // lane half

    int sj[8], row[16];
#pragma unroll
    for (int j = 0; j < 8; ++j)  sj[j]  = (j & 3) + 8 * (j >> 2) + 4 * hi;
#pragma unroll
    for (int r = 0; r < 16; ++r) row[r] = (r & 3) + 8 * (r >> 2) + 4 * hi;

    f32x16 zf;
#pragma unroll
    for (int r = 0; r < 16; ++r) zf[r] = 0.f;

    // ---- one-time: bvEff[m] = bv[m] + sum_t bf[t]*wv[t*32+m] ----
    float bve = bv[m];
#pragma unroll 8
    for (int t = 0; t < 32; ++t) bve = fmaf(wv[t * 32 + m], bf[t], bve);

    // ---- one-time: Wc = WF·WVf via 2 MFMA32s ----
    f16x8 afw1, afw2, bwv1, bwv2;
#pragma unroll
    for (int j = 0; j < 8; ++j) {
        const int k = sj[j];
        afw1[j] = (f16)wf[m * 32 + k];
        afw2[j] = (f16)wf[m * 32 + 16 + k];
        bwv1[j] = (f16)wv[k * 32 + m];
        bwv2[j] = (f16)wv[(16 + k) * 32 + m];
    }
    f32x16 dwc = MFMA32(afw1, bwv1, zf);
    dwc = MFMA32(afw2, bwv2, dwc);
    f16x8 awclo, awchi;
#pragma unroll
    for (int j = 0; j < 8; ++j) {
        awclo[j] = (f16)dwc[j];
        awchi[j] = (f16)dwc[8 + j];
    }

    // ---- one-time weight fragment gathers (all cached loads) ----
    f16x8 aw0x, awv2x, aw1lo, aw1hi, awrlo, awrhi;
#pragma unroll
    for (int j = 0; j < 8; ++j) {
        const int k = sj[j];
        aw0x[j]  = (k < 3) ? (f16)w0[k * 32 + m]
                  : (k == 3 ? (f16)b0[m] : (f16)0.f);
        awv2x[j] = (k >= 4 && k < 7) ? (f16)wv[(32 + (k - 4)) * 32 + m]
                  : (k == 7 ? (f16)bve : (f16)0.f);
        aw1lo[j] = (f16)w1[k * 32 + m];
        aw1hi[j] = (f16)w1[(16 + k) * 32 + m];
        awrlo[j] = (m < 3) ? (f16)wr[k * 3 + m] : (f16)0.f;
        awrhi[j] = (m < 3) ? (f16)wr[(16 + k) * 3 + m] : (f16)0.f;
    }

    // sigma weights packed f16: word w pairs channels (row[2w], row[2w+1])
    unsigned wspk[8];
#pragma unroll
    for (int w = 0; w < 8; ++w)
        wspk[w] = pkrtz(ws[row[2 * w]], ws[row[2 * w + 1]]);

    // L1 bias C-init
    f32x16 b1c;
#pragma unroll
    for (int r = 0; r < 16; ++r) b1c[r] = b1[row[r]];

    const float br0 = br[0], br1 = br[1], br2 = br[2], bs0 = bs[0];

    const int wslot  = blockIdx.x * 4 + (threadIdx.x >> 6);
    const int nslots = gridDim.x * 4;   // 8192 waves

    // ---- prologue: load x(wslot), build bx, issue its L0 + cv ----
    f32x16 c0c, cvc;
    {
        const float2* xp2 = reinterpret_cast<const float2*>(
            x + (size_t)(wslot * 32 + m) * 6);
        const float2 a0 = xp2[0], a1 = xp2[1], a2 = xp2[2];
        const float fa = hi ? a1.y : a0.x;
        const float fb = hi ? a2.x : a0.y;
        const float fc = hi ? a2.y : a1.x;
        H8 bxc;
        bxc.u[0] = pkrtz(fa, fb);
        bxc.u[1] = pkrtz(fc, 1.0f);
        bxc.u[2] = 0u;
        bxc.u[3] = 0u;
        c0c = MFMA32(aw0x, bxc.v, zf);
        cvc = MFMA32(awv2x, bxc.v, zf);
    }
    // prefetch x for the next tile
    float2 nx0, nx1, nx2;
    {
        int pn = wslot + nslots; if (pn >= NT32) pn = wslot;
        const float2* xp2 = reinterpret_cast<const float2*>(
            x + (size_t)(pn * 32 + m) * 6);
        nx0 = xp2[0]; nx1 = xp2[1]; nx2 = xp2[2];
    }

#pragma unroll 2
    for (int tile = wslot; tile < NT32; tile += nslots) {
        int tn  = tile + nslots; if (tn  >= NT32) tn  = wslot;
        int tn2 = tn   + nslots; if (tn2 >= NT32) tn2 = wslot;

        // build NEXT tile's input fragment from prefetched regs
        const float fa = hi ? nx1.y : nx0.x;
        const float fb = hi ? nx2.x : nx0.y;
        const float fc = hi ? nx2.y : nx1.x;
        H8 bxn;
        bxn.u[0] = pkrtz(fa, fb);
        bxn.u[1] = pkrtz(fc, 1.0f);
        bxn.u[2] = 0u;
        bxn.u[3] = 0u;

        // issue loads for tile t+2
        {
            const float2* xq = reinterpret_cast<const float2*>(
                x + (size_t)(tn2 * 32 + m) * 6);
            nx0 = xq[0]; nx1 = xq[1]; nx2 = xq[2];
        }

        // ---- pack h0 from c0c (computed a full iteration ago) ----
        H8 blo, bhi;
        blo.u[0] = relu2(pkrtz(c0c[0], c0c[1]));
        blo.u[1] = relu2(pkrtz(c0c[2], c0c[3]));
        blo.u[2] = relu2(pkrtz(c0c[4], c0c[5]));
        blo.u[3] = relu2(pkrtz(c0c[6], c0c[7]));
        bhi.u[0] = relu2(pkrtz(c0c[8], c0c[9]));
        bhi.u[1] = relu2(pkrtz(c0c[10], c0c[11]));
        bhi.u[2] = relu2(pkrtz(c0c[12], c0c[13]));
        bhi.u[3] = relu2(pkrtz(c0c[14], c0c[15]));

        // ---- issue NEXT tile's L0 + view-partial (independent of below) ----
        f32x16 c0n = MFMA32(aw0x, bxn.v, zf);
        f32x16 cvn = MFMA32(awv2x, bxn.v, zf);

        // ---- layer 1: 32 -> 32 (+b1 via C-init), relu ----
        f32x16 c1 = MFMA32(aw1lo, blo.v, b1c);
        c1 = MFMA32(aw1hi, bhi.v, c1);

        blo.u[0] = relu2(pkrtz(c1[0], c1[1]));
        blo.u[1] = relu2(pkrtz(c1[2], c1[3]));
        blo.u[2] = relu2(pkrtz(c1[4], c1[5]));
        blo.u[3] = relu2(pkrtz(c1[6], c1[7]));
        bhi.u[0] = relu2(pkrtz(c1[8], c1[9]));
        bhi.u[1] = relu2(pkrtz(c1[10], c1[11]));
        bhi.u[2] = relu2(pkrtz(c1[12], c1[13]));
        bhi.u[3] = relu2(pkrtz(c1[14], c1[15]));

        // sigma = ws . relu(h1) via packed dot2 (f32 accumulate)
        float s0 = 0.f, s1 = 0.f;
#pragma unroll
        for (int w = 0; w < 4; ++w) {
            s0 = fdot2(blo.u[w], wspk[w], s0);
            s1 = fdot2(bhi.u[w], wspk[4 + w], s1);
        }
        float sg = s0 + s1;
        sg += __shfl_xor(sg, 32);

        // ---- folded feature+view layer: h1·Wc + cvc (ready), relu ----
        f32x16 cc = MFMA32(awclo, blo.v, cvc);
        cc = MFMA32(awchi, bhi.v, cc);

        blo.u[0] = relu2(pkrtz(cc[0], cc[1]));
        blo.u[1] = relu2(pkrtz(cc[2], cc[3]));
        blo.u[2] = relu2(pkrtz(cc[4], cc[5]));
        blo.u[3] = relu2(pkrtz(cc[6], cc[7]));
        bhi.u[0] = relu2(pkrtz(cc[8], cc[9]));
        bhi.u[1] = relu2(pkrtz(cc[10], cc[11]));
        bhi.u[2] = relu2(pkrtz(cc[12], cc[13]));
        bhi.u[3] = relu2(pkrtz(cc[14], cc[15]));

        // ---- rgb: 32 -> 3 (rows 0..2 valid; +br at store) ----
        f32x16 cr = MFMA32(awrlo, blo.v, zf);
        cr = MFMA32(awrhi, bhi.v, cr);

        // ---- store: hi==0 lanes hold rgb rows 0..2 for their point ----
        if (hi == 0) {
            float4 o = make_float4(cr[0] + br0, cr[1] + br1,
                                   cr[2] + br2, sg + bs0);
            *reinterpret_cast<float4*>(out + (size_t)(tile * 32 + m) * 4) = o;
        }

        // rotate pipeline state
        c0c = c0n;
        cvc = cvn;
    }
}

extern "C" void kernel_launch(void* const* d_in, const int* in_sizes, int n_in,
                              void* d_out, int out_size, void* d_ws, size_t ws_size,
                              hipStream_t stream) {
    const float* x  = (const float*)d_in[0];
    const float* w0 = (const float*)d_in[1];
    const float* b0 = (const float*)d_in[2];
    const float* w1 = (const float*)d_in[3];
    const float* b1 = (const float*)d_in[4];
    const float* wf = (const float*)d_in[5];
    const float* bf = (const float*)d_in[6];
    const float* ws = (const float*)d_in[7];
    const float* bs = (const float*)d_in[8];
    const float* wv = (const float*)d_in[9];
    const float* bv = (const float*)d_in[10];
    const float* wr = (const float*)d_in[11];
    const float* br = (const float*)d_in[12];
    float* out = (float*)d_out;

    dim3 block(256);
    dim3 grid(2048);
    kilonerf_r20<<<grid, block, 0, stream>>>(x, w0, b0, w1, b1, wf, bf,
                                             ws, bs, wv, bv, wr, br, out);
}

// Round 21
// 52.539 us; speedup vs baseline: 1.1458x; 1.0956x over previous
//
#include <hip/hip_runtime.h>

// KiloNeRF fused MLP — 32x32x16 MFMA, layer-folded, single-kernel,
// FULLY-RESIDENT GRID version.
// R21 = R18 (best, 55.25us) with grid shrunk 2048 -> 768 blocks
// (= 3 blocks/CU, matching measured residency): all waves co-resident,
// single batch, one-time setup (bve loop, Wc 2xMFMA compose, ~50 weight
// gathers) amortized over ~43 tiles/wave instead of 16, no inter-batch
// drain/fill tails. Inner loop identical to R18.
//   main chain per 32-pt tile (6 MFMAs):
//   bx -> L0(+b0) -> L1(+b1) -> fold(h1·Wc + cv) -> rgb ; sigma via fdot2;
//   cv (views+bvEff) off the critical path; br/bs at store; x prefetch.

#define NPTS   4194304
#define NT32   (NPTS / 32)

typedef _Float16 f16;
typedef _Float16 f16x2 __attribute__((ext_vector_type(2)));
typedef _Float16 f16x8 __attribute__((ext_vector_type(8)));
typedef __fp16   h16x2 __attribute__((ext_vector_type(2)));
typedef float    f32x16 __attribute__((ext_vector_type(16)));

union H8 { f16x8 v; unsigned u[4]; };

static __device__ __forceinline__ unsigned pkrtz(float a, float b) {
    return __builtin_bit_cast(unsigned, __builtin_amdgcn_cvt_pkrtz(a, b));
}
static __device__ __forceinline__ unsigned relu2(unsigned w) {
    f16x2 h = __builtin_bit_cast(f16x2, w);
    f16x2 z = (f16x2)(f16)0.f;
    return __builtin_bit_cast(unsigned, __builtin_elementwise_max(h, z));
}
static __device__ __forceinline__ float fdot2(unsigned a, unsigned b, float c) {
    return __builtin_amdgcn_fdot2(__builtin_bit_cast(h16x2, a),
                                  __builtin_bit_cast(h16x2, b), c, false);
}

#define MFMA32(A, B, C) __builtin_amdgcn_mfma_f32_32x32x16_f16((A), (B), (C), 0, 0, 0)

__global__ __launch_bounds__(256, 4) void kilonerf_r21(
    const float* __restrict__ x,
    const float* __restrict__ w0, const float* __restrict__ b0,
    const float* __restrict__ w1, const float* __restrict__ b1,
    const float* __restrict__ wf, const float* __restrict__ bf,
    const float* __restrict__ ws, const float* __restrict__ bs,
    const float* __restrict__ wv, const float* __restrict__ bv,
    const float* __restrict__ wr, const float* __restrict__ br,
    float* __restrict__ out)
{
    const int lane = threadIdx.x & 63;
    const int m  = lane & 31;     // output channel (A row) / point (B,C col)
    const int hi = lane >> 5;     // lane half

    int sj[8], row[16];
#pragma unroll
    for (int j = 0; j < 8; ++j)  sj[j]  = (j & 3) + 8 * (j >> 2) + 4 * hi;
#pragma unroll
    for (int r = 0; r < 16; ++r) row[r] = (r & 3) + 8 * (r >> 2) + 4 * hi;

    f32x16 zf;
#pragma unroll
    for (int r = 0; r < 16; ++r) zf[r] = 0.f;

    // ---- one-time: bvEff[m] = bv[m] + sum_t bf[t]*wv[t*32+m] ----
    float bve = bv[m];
#pragma unroll 8
    for (int t = 0; t < 32; ++t) bve = fmaf(wv[t * 32 + m], bf[t], bve);

    // ---- one-time: Wc = WF·WVf via 2 MFMA32s ----
    f16x8 afw1, afw2, bwv1, bwv2;
#pragma unroll
    for (int j = 0; j < 8; ++j) {
        const int k = sj[j];
        afw1[j] = (f16)wf[m * 32 + k];
        afw2[j] = (f16)wf[m * 32 + 16 + k];
        bwv1[j] = (f16)wv[k * 32 + m];
        bwv2[j] = (f16)wv[(16 + k) * 32 + m];
    }
    f32x16 dwc = MFMA32(afw1, bwv1, zf);
    dwc = MFMA32(afw2, bwv2, dwc);
    f16x8 awclo, awchi;
#pragma unroll
    for (int j = 0; j < 8; ++j) {
        awclo[j] = (f16)dwc[j];
        awchi[j] = (f16)dwc[8 + j];
    }

    // ---- one-time weight fragment gathers (all cached loads) ----
    f16x8 aw0x, awv2x, aw1lo, aw1hi, awrlo, awrhi;
#pragma unroll
    for (int j = 0; j < 8; ++j) {
        const int k = sj[j];
        aw0x[j]  = (k < 3) ? (f16)w0[k * 32 + m]
                  : (k == 3 ? (f16)b0[m] : (f16)0.f);
        awv2x[j] = (k >= 4 && k < 7) ? (f16)wv[(32 + (k - 4)) * 32 + m]
                  : (k == 7 ? (f16)bve : (f16)0.f);
        aw1lo[j] = (f16)w1[k * 32 + m];
        aw1hi[j] = (f16)w1[(16 + k) * 32 + m];
        awrlo[j] = (m < 3) ? (f16)wr[k * 3 + m] : (f16)0.f;
        awrhi[j] = (m < 3) ? (f16)wr[(16 + k) * 3 + m] : (f16)0.f;
    }

    // sigma weights packed f16: word w pairs channels (row[2w], row[2w+1])
    unsigned wspk[8];
#pragma unroll
    for (int w = 0; w < 8; ++w)
        wspk[w] = pkrtz(ws[row[2 * w]], ws[row[2 * w + 1]]);

    // L1 bias C-init
    f32x16 b1c;
#pragma unroll
    for (int r = 0; r < 16; ++r) b1c[r] = b1[row[r]];

    const float br0 = br[0], br1 = br[1], br2 = br[2], bs0 = bs[0];

    const int wslot  = blockIdx.x * 4 + (threadIdx.x >> 6);
    const int nslots = gridDim.x * 4;   // 3072 waves, fully resident

    // ---- prefetch first tile's x ----
    float2 cx0, cx1, cx2;
    {
        const float2* xp2 = reinterpret_cast<const float2*>(
            x + (size_t)(wslot * 32 + m) * 6);
        cx0 = xp2[0]; cx1 = xp2[1]; cx2 = xp2[2];
    }

    for (int tile = wslot; tile < NT32; tile += nslots) {
        // issue next tile's loads early (wraps to a valid address at end)
        int np = tile + nslots; if (np >= NT32) np = wslot;
        const float2* xn = reinterpret_cast<const float2*>(
            x + (size_t)(np * 32 + m) * 6);
        float2 nx0 = xn[0], nx1 = xn[1], nx2 = xn[2];

        // merged input fragment: hi=0 -> {p0,p1,p2,1} at k=0..3,
        //                        hi=1 -> {v0,v1,v2,1} at k=4..7
        const float fa = hi ? cx1.y : cx0.x;
        const float fb = hi ? cx2.x : cx0.y;
        const float fc = hi ? cx2.y : cx1.x;
        H8 bx;
        bx.u[0] = pkrtz(fa, fb);
        bx.u[1] = pkrtz(fc, 1.0f);
        bx.u[2] = 0u;
        bx.u[3] = 0u;

        // ---- layer 0: 3 -> 32 (+b0 via k=3), relu ----
        f32x16 c0 = MFMA32(aw0x, bx.v, zf);

        H8 blo, bhi;
        blo.u[0] = relu2(pkrtz(c0[0], c0[1]));
        blo.u[1] = relu2(pkrtz(c0[2], c0[3]));
        blo.u[2] = relu2(pkrtz(c0[4], c0[5]));
        blo.u[3] = relu2(pkrtz(c0[6], c0[7]));
        bhi.u[0] = relu2(pkrtz(c0[8], c0[9]));
        bhi.u[1] = relu2(pkrtz(c0[10], c0[11]));
        bhi.u[2] = relu2(pkrtz(c0[12], c0[13]));
        bhi.u[3] = relu2(pkrtz(c0[14], c0[15]));

        // ---- layer 1: 32 -> 32 (+b1 via C-init), relu ----
        f32x16 c1 = MFMA32(aw1lo, blo.v, b1c);
        c1 = MFMA32(aw1hi, bhi.v, c1);

        blo.u[0] = relu2(pkrtz(c1[0], c1[1]));
        blo.u[1] = relu2(pkrtz(c1[2], c1[3]));
        blo.u[2] = relu2(pkrtz(c1[4], c1[5]));
        blo.u[3] = relu2(pkrtz(c1[6], c1[7]));
        bhi.u[0] = relu2(pkrtz(c1[8], c1[9]));
        bhi.u[1] = relu2(pkrtz(c1[10], c1[11]));
        bhi.u[2] = relu2(pkrtz(c1[12], c1[13]));
        bhi.u[3] = relu2(pkrtz(c1[14], c1[15]));

        // sigma = ws . relu(h1) via packed dot2 (f32 accumulate)
        float s0 = 0.f, s1 = 0.f;
#pragma unroll
        for (int w = 0; w < 4; ++w) {
            s0 = fdot2(blo.u[w], wspk[w], s0);
            s1 = fdot2(bhi.u[w], wspk[4 + w], s1);
        }
        float sg = s0 + s1;
        sg += __shfl_xor(sg, 32);

        // ---- view partial (late): views(3)+bvEff from still-live bx ----
        f32x16 cv = MFMA32(awv2x, bx.v, zf);

        // ---- folded feature+view layer: h1·Wc + cv (in-place), relu ----
        cv = MFMA32(awclo, blo.v, cv);
        cv = MFMA32(awchi, bhi.v, cv);

        blo.u[0] = relu2(pkrtz(cv[0], cv[1]));
        blo.u[1] = relu2(pkrtz(cv[2], cv[3]));
        blo.u[2] = relu2(pkrtz(cv[4], cv[5]));
        blo.u[3] = relu2(pkrtz(cv[6], cv[7]));
        bhi.u[0] = relu2(pkrtz(cv[8], cv[9]));
        bhi.u[1] = relu2(pkrtz(cv[10], cv[11]));
        bhi.u[2] = relu2(pkrtz(cv[12], cv[13]));
        bhi.u[3] = relu2(pkrtz(cv[14], cv[15]));

        // ---- rgb: 32 -> 3 (rows 0..2 valid; +br at store) ----
        f32x16 cr = MFMA32(awrlo, blo.v, zf);
        cr = MFMA32(awrhi, bhi.v, cr);

        // ---- store: hi==0 lanes hold rgb rows 0..2 for their point ----
        if (hi == 0) {
            float4 o = make_float4(cr[0] + br0, cr[1] + br1,
                                   cr[2] + br2, sg + bs0);
            *reinterpret_cast<float4*>(out + (size_t)(tile * 32 + m) * 4) = o;
        }

        cx0 = nx0; cx1 = nx1; cx2 = nx2;
    }
}

extern "C" void kernel_launch(void* const* d_in, const int* in_sizes, int n_in,
                              void* d_out, int out_size, void* d_ws, size_t ws_size,
                              hipStream_t stream) {
    const float* x  = (const float*)d_in[0];
    const float* w0 = (const float*)d_in[1];
    const float* b0 = (const float*)d_in[2];
    const float* w1 = (const float*)d_in[3];
    const float* b1 = (const float*)d_in[4];
    const float* wf = (const float*)d_in[5];
    const float* bf = (const float*)d_in[6];
    const float* ws = (const float*)d_in[7];
    const float* bs = (const float*)d_in[8];
    const float* wv = (const float*)d_in[9];
    const float* bv = (const float*)d_in[10];
    const float* wr = (const float*)d_in[11];
    const float* br = (const float*)d_in[12];
    float* out = (float*)d_out;

    dim3 block(256);
    dim3 grid(768);   // 3 blocks/CU: fully resident, single batch
    kilonerf_r21<<<grid, block, 0, stream>>>(x, w0, b0, w1, b1, wf, bf,
                                             ws, bs, wv, bv, wr, br, out);
}

// Round 22
// 52.251 us; speedup vs baseline: 1.1521x; 1.0055x over previous
//
#include <hip/hip_runtime.h>

// KiloNeRF fused MLP — 32x32x16 MFMA, layer-folded, fully-resident grid,
// setprio version.
// R22 = R21 (best, 52.54us) + s_setprio(1) around the serial MFMA chain
// (L1 -> fold -> rgb). Precedent: learn_hip m191 — setprio gives +4-7% on
// independent-wave kernels at different phases (attn), null on lockstep
// GEMM. This kernel is the attn-like regime: 12 independent waves/CU in
// deep MFMA<->VALU chains; priority biases the scheduler toward the wave
// inside its chain, breaking convoy-aligned stalls.
//   main chain per 32-pt tile (6 MFMAs):
//   bx -> L0(+b0) -> L1(+b1) -> fold(h1·Wc + cv) -> rgb ; sigma via fdot2;
//   cv (views+bvEff) off the critical path; br/bs at store; x prefetch;
//   grid = 768 blocks (3/CU, single batch, fully resident).

#define NPTS   4194304
#define NT32   (NPTS / 32)

typedef _Float16 f16;
typedef _Float16 f16x2 __attribute__((ext_vector_type(2)));
typedef _Float16 f16x8 __attribute__((ext_vector_type(8)));
typedef __fp16   h16x2 __attribute__((ext_vector_type(2)));
typedef float    f32x16 __attribute__((ext_vector_type(16)));

union H8 { f16x8 v; unsigned u[4]; };

static __device__ __forceinline__ unsigned pkrtz(float a, float b) {
    return __builtin_bit_cast(unsigned, __builtin_amdgcn_cvt_pkrtz(a, b));
}
static __device__ __forceinline__ unsigned relu2(unsigned w) {
    f16x2 h = __builtin_bit_cast(f16x2, w);
    f16x2 z = (f16x2)(f16)0.f;
    return __builtin_bit_cast(unsigned, __builtin_elementwise_max(h, z));
}
static __device__ __forceinline__ float fdot2(unsigned a, unsigned b, float c) {
    return __builtin_amdgcn_fdot2(__builtin_bit_cast(h16x2, a),
                                  __builtin_bit_cast(h16x2, b), c, false);
}

#define MFMA32(A, B, C) __builtin_amdgcn_mfma_f32_32x32x16_f16((A), (B), (C), 0, 0, 0)

__global__ __launch_bounds__(256, 4) void kilonerf_r22(
    const float* __restrict__ x,
    const float* __restrict__ w0, const float* __restrict__ b0,
    const float* __restrict__ w1, const float* __restrict__ b1,
    const float* __restrict__ wf, const float* __restrict__ bf,
    const float* __restrict__ ws, const float* __restrict__ bs,
    const float* __restrict__ wv, const float* __restrict__ bv,
    const float* __restrict__ wr, const float* __restrict__ br,
    float* __restrict__ out)
{
    const int lane = threadIdx.x & 63;
    const int m  = lane & 31;     // output channel (A row) / point (B,C col)
    const int hi = lane >> 5;     // lane half

    int sj[8], row[16];
#pragma unroll
    for (int j = 0; j < 8; ++j)  sj[j]  = (j & 3) + 8 * (j >> 2) + 4 * hi;
#pragma unroll
    for (int r = 0; r < 16; ++r) row[r] = (r & 3) + 8 * (r >> 2) + 4 * hi;

    f32x16 zf;
#pragma unroll
    for (int r = 0; r < 16; ++r) zf[r] = 0.f;

    // ---- one-time: bvEff[m] = bv[m] + sum_t bf[t]*wv[t*32+m] ----
    float bve = bv[m];
#pragma unroll 8
    for (int t = 0; t < 32; ++t) bve = fmaf(wv[t * 32 + m], bf[t], bve);

    // ---- one-time: Wc = WF·WVf via 2 MFMA32s ----
    f16x8 afw1, afw2, bwv1, bwv2;
#pragma unroll
    for (int j = 0; j < 8; ++j) {
        const int k = sj[j];
        afw1[j] = (f16)wf[m * 32 + k];
        afw2[j] = (f16)wf[m * 32 + 16 + k];
        bwv1[j] = (f16)wv[k * 32 + m];
        bwv2[j] = (f16)wv[(16 + k) * 32 + m];
    }
    f32x16 dwc = MFMA32(afw1, bwv1, zf);
    dwc = MFMA32(afw2, bwv2, dwc);
    f16x8 awclo, awchi;
#pragma unroll
    for (int j = 0; j < 8; ++j) {
        awclo[j] = (f16)dwc[j];
        awchi[j] = (f16)dwc[8 + j];
    }

    // ---- one-time weight fragment gathers (all cached loads) ----
    f16x8 aw0x, awv2x, aw1lo, aw1hi, awrlo, awrhi;
#pragma unroll
    for (int j = 0; j < 8; ++j) {
        const int k = sj[j];
        aw0x[j]  = (k < 3) ? (f16)w0[k * 32 + m]
                  : (k == 3 ? (f16)b0[m] : (f16)0.f);
        awv2x[j] = (k >= 4 && k < 7) ? (f16)wv[(32 + (k - 4)) * 32 + m]
                  : (k == 7 ? (f16)bve : (f16)0.f);
        aw1lo[j] = (f16)w1[k * 32 + m];
        aw1hi[j] = (f16)w1[(16 + k) * 32 + m];
        awrlo[j] = (m < 3) ? (f16)wr[k * 3 + m] : (f16)0.f;
        awrhi[j] = (m < 3) ? (f16)wr[(16 + k) * 3 + m] : (f16)0.f;
    }

    // sigma weights packed f16: word w pairs channels (row[2w], row[2w+1])
    unsigned wspk[8];
#pragma unroll
    for (int w = 0; w < 8; ++w)
        wspk[w] = pkrtz(ws[row[2 * w]], ws[row[2 * w + 1]]);

    // L1 bias C-init
    f32x16 b1c;
#pragma unroll
    for (int r = 0; r < 16; ++r) b1c[r] = b1[row[r]];

    const float br0 = br[0], br1 = br[1], br2 = br[2], bs0 = bs[0];

    const int wslot  = blockIdx.x * 4 + (threadIdx.x >> 6);
    const int nslots = gridDim.x * 4;   // 3072 waves, fully resident

    // ---- prefetch first tile's x ----
    float2 cx0, cx1, cx2;
    {
        const float2* xp2 = reinterpret_cast<const float2*>(
            x + (size_t)(wslot * 32 + m) * 6);
        cx0 = xp2[0]; cx1 = xp2[1]; cx2 = xp2[2];
    }

    for (int tile = wslot; tile < NT32; tile += nslots) {
        // issue next tile's loads early (wraps to a valid address at end)
        int np = tile + nslots; if (np >= NT32) np = wslot;
        const float2* xn = reinterpret_cast<const float2*>(
            x + (size_t)(np * 32 + m) * 6);
        float2 nx0 = xn[0], nx1 = xn[1], nx2 = xn[2];

        // merged input fragment: hi=0 -> {p0,p1,p2,1} at k=0..3,
        //                        hi=1 -> {v0,v1,v2,1} at k=4..7
        const float fa = hi ? cx1.y : cx0.x;
        const float fb = hi ? cx2.x : cx0.y;
        const float fc = hi ? cx2.y : cx1.x;
        H8 bx;
        bx.u[0] = pkrtz(fa, fb);
        bx.u[1] = pkrtz(fc, 1.0f);
        bx.u[2] = 0u;
        bx.u[3] = 0u;

        // ---- layer 0: 3 -> 32 (+b0 via k=3), relu ----
        f32x16 c0 = MFMA32(aw0x, bx.v, zf);

        H8 blo, bhi;
        blo.u[0] = relu2(pkrtz(c0[0], c0[1]));
        blo.u[1] = relu2(pkrtz(c0[2], c0[3]));
        blo.u[2] = relu2(pkrtz(c0[4], c0[5]));
        blo.u[3] = relu2(pkrtz(c0[6], c0[7]));
        bhi.u[0] = relu2(pkrtz(c0[8], c0[9]));
        bhi.u[1] = relu2(pkrtz(c0[10], c0[11]));
        bhi.u[2] = relu2(pkrtz(c0[12], c0[13]));
        bhi.u[3] = relu2(pkrtz(c0[14], c0[15]));

        // ---- critical chain: raise wave priority (T5, attn-regime) ----
        __builtin_amdgcn_s_setprio(1);

        // ---- layer 1: 32 -> 32 (+b1 via C-init), relu ----
        f32x16 c1 = MFMA32(aw1lo, blo.v, b1c);
        c1 = MFMA32(aw1hi, bhi.v, c1);

        blo.u[0] = relu2(pkrtz(c1[0], c1[1]));
        blo.u[1] = relu2(pkrtz(c1[2], c1[3]));
        blo.u[2] = relu2(pkrtz(c1[4], c1[5]));
        blo.u[3] = relu2(pkrtz(c1[6], c1[7]));
        bhi.u[0] = relu2(pkrtz(c1[8], c1[9]));
        bhi.u[1] = relu2(pkrtz(c1[10], c1[11]));
        bhi.u[2] = relu2(pkrtz(c1[12], c1[13]));
        bhi.u[3] = relu2(pkrtz(c1[14], c1[15]));

        // sigma = ws . relu(h1) via packed dot2 (f32 accumulate)
        float s0 = 0.f, s1 = 0.f;
#pragma unroll
        for (int w = 0; w < 4; ++w) {
            s0 = fdot2(blo.u[w], wspk[w], s0);
            s1 = fdot2(bhi.u[w], wspk[4 + w], s1);
        }
        float sg = s0 + s1;
        sg += __shfl_xor(sg, 32);

        // ---- view partial (late): views(3)+bvEff from still-live bx ----
        f32x16 cv = MFMA32(awv2x, bx.v, zf);

        // ---- folded feature+view layer: h1·Wc + cv (in-place), relu ----
        cv = MFMA32(awclo, blo.v, cv);
        cv = MFMA32(awchi, bhi.v, cv);

        blo.u[0] = relu2(pkrtz(cv[0], cv[1]));
        blo.u[1] = relu2(pkrtz(cv[2], cv[3]));
        blo.u[2] = relu2(pkrtz(cv[4], cv[5]));
        blo.u[3] = relu2(pkrtz(cv[6], cv[7]));
        bhi.u[0] = relu2(pkrtz(cv[8], cv[9]));
        bhi.u[1] = relu2(pkrtz(cv[10], cv[11]));
        bhi.u[2] = relu2(pkrtz(cv[12], cv[13]));
        bhi.u[3] = relu2(pkrtz(cv[14], cv[15]));

        // ---- rgb: 32 -> 3 (rows 0..2 valid; +br at store) ----
        f32x16 cr = MFMA32(awrlo, blo.v, zf);
        cr = MFMA32(awrhi, bhi.v, cr);

        __builtin_amdgcn_s_setprio(0);

        // ---- store: hi==0 lanes hold rgb rows 0..2 for their point ----
        if (hi == 0) {
            float4 o = make_float4(cr[0] + br0, cr[1] + br1,
                                   cr[2] + br2, sg + bs0);
            *reinterpret_cast<float4*>(out + (size_t)(tile * 32 + m) * 4) = o;
        }

        cx0 = nx0; cx1 = nx1; cx2 = nx2;
    }
}

extern "C" void kernel_launch(void* const* d_in, const int* in_sizes, int n_in,
                              void* d_out, int out_size, void* d_ws, size_t ws_size,
                              hipStream_t stream) {
    const float* x  = (const float*)d_in[0];
    const float* w0 = (const float*)d_in[1];
    const float* b0 = (const float*)d_in[2];
    const float* w1 = (const float*)d_in[3];
    const float* b1 = (const float*)d_in[4];
    const float* wf = (const float*)d_in[5];
    const float* bf = (const float*)d_in[6];
    const float* ws = (const float*)d_in[7];
    const float* bs = (const float*)d_in[8];
    const float* wv = (const float*)d_in[9];
    const float* bv = (const float*)d_in[10];
    const float* wr = (const float*)d_in[11];
    const float* br = (const float*)d_in[12];
    float* out = (float*)d_out;

    dim3 block(256);
    dim3 grid(768);   // 3 blocks/CU: fully resident, single batch
    kilonerf_r22<<<grid, block, 0, stream>>>(x, w0, b0, w1, b1, wf, bf,
                                             ws, bs, wv, bv, wr, br, out);
}